// Round 12
// baseline (193.169 us; speedup 1.0000x reference)
//
#include <hip/hip_runtime.h>
#include <math.h>

// Network_22892175688023 — round 22 (= R19 resubmit #3; R9/R11 GPU-acquisition
// timeouts, R10 container failure — kernel has never executed; hang-audit clean
// twice: 1-block/CU co-residency, R17-proven tree barrier, uniform barriers,
// R12-verbatim indexing). LDS-staged multi-msub generator. 2 stages.
//   R18 post-mortem: gen time invariant vs waves×VGPR -> per-CU L2-request
//   (MSHR x latency) bound on the 2.25 MB/CU E-plane stream. Fix: 4 msubs/block
//   share each staged B-slab -> 850 KB/CU. 64 blk = 16 mg x 4 g(ns-quarter).
//   P1 enc2 (blk=msub)            [R17 verbatim]          -> gbar
//   P2a gate (blk=msub) + bcg stA [R17 verbatim]          -> gbar
//   P2b gen1: stage 32KB/e LDS, 8 waves=(4 msub x 2 ns-pair), A1 slices stA -> gbar
//   P3  gen2: same structure, A1 full via ld16A, A2 slices stA             -> gbar
//   P4  gen3 (blk=msub)           [R12 verbatim, A2 ld16A]
//   All MFMA/blend orders byte-identical (B passes through LDS unchanged).

#define DIN 103
#define NE  8
#define HH  256
#define DOUT 51
#define EPSBN 1e-5f

typedef __attribute__((ext_vector_type(8))) short bf16x8;
typedef __attribute__((ext_vector_type(4))) float f32x4;
typedef __attribute__((ext_vector_type(8))) unsigned short us8;
typedef unsigned short ushort_t;

__device__ __forceinline__ float eluf(float v) { return v > 0.f ? v : (expf(v) - 1.f); }
__device__ __forceinline__ unsigned short bf16h(float f) {
  unsigned u = __float_as_uint(f);
  u += 0x7FFFu + ((u >> 16) & 1u);
  return (unsigned short)(u >> 16);
}
__device__ __forceinline__ float bf16f(unsigned short h) { return __uint_as_float(((unsigned)h) << 16); }
__device__ __forceinline__ void split_bf16(float v, unsigned short& h, unsigned short& l) {
  h = bf16h(v);
  l = bf16h(v - bf16f(h));
}
#define MFMA __builtin_amdgcn_mfma_f32_16x16x32_bf16

// relaxed agent-scope coherent access helpers (no cache-maintenance ops)
__device__ __forceinline__ void stA(float* p, float v) {
  __hip_atomic_store(p, v, __ATOMIC_RELAXED, __HIP_MEMORY_SCOPE_AGENT);
}
__device__ __forceinline__ float ldA(const float* p) {
  return __hip_atomic_load((float*)p, __ATOMIC_RELAXED, __HIP_MEMORY_SCOPE_AGENT);
}
__device__ __forceinline__ void stAu(unsigned* p, unsigned v) {
  __hip_atomic_store(p, v, __ATOMIC_RELAXED, __HIP_MEMORY_SCOPE_AGENT);
}
__device__ __forceinline__ unsigned ldAu(const unsigned* p) {
  return __hip_atomic_load((unsigned*)p, __ATOMIC_RELAXED, __HIP_MEMORY_SCOPE_AGENT);
}
union U16B { us8 v; bf16x8 b; unsigned u[4]; };
__device__ __forceinline__ void st16A(void* p, us8 x) {
  U16B t; t.v = x;
  unsigned* d = (unsigned*)p;
#pragma unroll
  for (int j = 0; j < 4; ++j) stAu(d + j, t.u[j]);
}
__device__ __forceinline__ bf16x8 ld16A(const void* p) {
  U16B t;
  const unsigned* s = (const unsigned*)p;
#pragma unroll
  for (int j = 0; j < 4; ++j) t.u[j] = ldAu(s + j);
  return t.b;
}

// ---- ws layout (float offsets) ----
#define O_SLOTS1 0        // [64][128]
#define O_SLOTS2 8192     // [64][64]
#define O_BCG    12288    // [1024][8]
#define O_H1RAW  20480    // [1024][64]
#define O_XSH    118784   // [64 msub][4 kc][512] sh
#define O_XSL    184320
#define O_E1H    258048   // [8 e][16 ns][4 kc][512] sh
#define O_E1L    389120
#define O_E2H    520192   // [8 e][16 ns][8 kc][512] sh  (hi only)
#define O_E3H    782336   // [8 e][4 ns][8 kc][512] sh   (hi only)
#define O_A1H    847872   // [64 m][8 kc][512] sh
#define O_A1L    978944
#define O_A2H    1110016
#define O_A2L    1241088
#define O_BAR    1372160  // 4 x 1024-dword tree-barrier regions (zeroed by K1)

// 8x8 tree barrier for 64 blocks; region: grp[i]@i*32 (i<8), root@256,
// rel[j]@288+j*32 (j<8). Each region used once per launch.
__device__ __forceinline__ void gbar64(unsigned* base, int blk) {
  asm volatile("s_waitcnt vmcnt(0)" ::: "memory");
  __syncthreads();
  if (threadIdx.x == 0) {
    unsigned a = __hip_atomic_fetch_add(base + (blk >> 3) * 32, 1u,
                                        __ATOMIC_RELAXED, __HIP_MEMORY_SCOPE_AGENT);
    if (a == 7u) {
      unsigned r = __hip_atomic_fetch_add(base + 256, 1u,
                                          __ATOMIC_RELAXED, __HIP_MEMORY_SCOPE_AGENT);
      if (r == 7u) {
#pragma unroll
        for (int j = 0; j < 8; ++j) stAu(base + 288 + j * 32, 1u);
      }
    }
    while (ldAu(base + 288 + (blk & 7) * 32) == 0u)
      __builtin_amdgcn_s_sleep(2);
  }
  __syncthreads();
}

// ================= K1: prep planes + Xs frags + enc L1 (VALU) =================
// blocks: E2 0..255 | E1 256..383 | E3 384..447 | Xs 448..511 | enc1 512..575
__global__ __launch_bounds__(256) void k_prep_enc1(
    const float* __restrict__ x, const float* __restrict__ w1, const float* __restrict__ b1,
    const float* __restrict__ ew1, const float* __restrict__ ew2, const float* __restrict__ ew3,
    float* __restrict__ ws) {
  __shared__ union {
    float tile[32][65];
    float xt[16][104];
    struct { float w1L[64 * DIN]; float xr[16][104]; float hb[16][64]; } e1;
  } sm;
  int bk = blockIdx.x, t = threadIdx.x;
  int l2 = t & 63, c = l2 & 15, q = l2 >> 4;
  if (bk < 4) {   // zero the 4 barrier regions (1024 dwords each)
    unsigned* bz = (unsigned*)(ws + O_BAR) + bk * 1024;
#pragma unroll
    for (int i = 0; i < 4; ++i) bz[t + i * 256] = 0u;
  }

  if (bk < 256) {          // ---- E2: K=256, N=256, hi only ----
    int nh = bk & 3, kc = (bk >> 2) & 7, e = bk >> 5;
    int k0 = kc * 32, n0 = nh * 64;
#pragma unroll
    for (int i = 0; i < 8; ++i) {
      int kl = (t >> 6) + i * 4;
      sm.tile[kl][t & 63] = ew2[((size_t)e * HH + k0 + kl) * HH + n0 + (t & 63)];
    }
    __syncthreads();
    int nsl = t >> 6;
    us8 H8;
#pragma unroll
    for (int j = 0; j < 8; ++j) H8[j] = bf16h(sm.tile[q * 8 + j][nsl * 16 + c]);
    size_t dst = (((size_t)(e * 16 + nh * 4 + nsl)) * 8 + kc) * 512 + l2 * 8;
    *(us8*)((ushort_t*)(ws + O_E2H) + dst) = H8;
  } else if (bk < 384) {   // ---- E1: K=103->128, N=256, hi+lo ----
    int b2 = bk - 256;
    int nh = b2 & 3, kc = (b2 >> 2) & 3, e = b2 >> 4;
    int k0 = kc * 32, n0 = nh * 64;
#pragma unroll
    for (int i = 0; i < 8; ++i) {
      int kl = (t >> 6) + i * 4;
      int k = k0 + kl;
      sm.tile[kl][t & 63] = (k < DIN) ? ew1[((size_t)e * DIN + k) * HH + n0 + (t & 63)] : 0.f;
    }
    __syncthreads();
    int nsl = t >> 6;
    us8 H8, L8;
#pragma unroll
    for (int j = 0; j < 8; ++j) {
      unsigned short h, lo; split_bf16(sm.tile[q * 8 + j][nsl * 16 + c], h, lo);
      H8[j] = h; L8[j] = lo;
    }
    size_t dst = (((size_t)(e * 16 + nh * 4 + nsl)) * 4 + kc) * 512 + l2 * 8;
    *(us8*)((ushort_t*)(ws + O_E1H) + dst) = H8;
    *(us8*)((ushort_t*)(ws + O_E1L) + dst) = L8;
  } else if (bk < 448) {   // ---- E3: K=256, N=51->64, hi only ----
    int b2 = bk - 384;
    int kc = b2 & 7, e = b2 >> 3;
    int k0 = kc * 32;
#pragma unroll
    for (int i = 0; i < 8; ++i) {
      int kl = (t >> 6) + i * 4;
      int n = t & 63;
      sm.tile[kl][n] = (n < DOUT) ? ew3[((size_t)e * HH + k0 + kl) * DOUT + n] : 0.f;
    }
    __syncthreads();
    int nsl = t >> 6;
    us8 H8;
#pragma unroll
    for (int j = 0; j < 8; ++j) H8[j] = bf16h(sm.tile[q * 8 + j][nsl * 16 + c]);
    size_t dst = (((size_t)(e * 4 + nsl)) * 8 + kc) * 512 + l2 * 8;
    *(us8*)((ushort_t*)(ws + O_E3H) + dst) = H8;
  } else if (bk < 512) {   // ---- Xs: A-fragments of scaled x, 16 rows/block, hi+lo ----
    int msub = bk - 448;
    for (int i = t; i < 16 * 104; i += 256) {
      int b = i / 104, k = i - b * 104;
      float v = 0.f;
      if (k < DIN) { v = x[(size_t)(msub * 16 + b) * DIN + k]; if (k >= 100) v *= 100.f; }
      sm.xt[b][k] = v;
    }
    __syncthreads();
    int kc = t >> 6;
    int m = c;
    us8 H8, L8;
#pragma unroll
    for (int j = 0; j < 8; ++j) {
      int k = kc * 32 + q * 8 + j;
      float v = (k < 104) ? sm.xt[m][k] : 0.f;
      unsigned short h, lo; split_bf16(v, h, lo);
      H8[j] = h; L8[j] = lo;
    }
    size_t dst = ((size_t)msub * 4 + kc) * 512 + l2 * 8;
    *(us8*)((ushort_t*)(ws + O_XSH) + dst) = H8;
    *(us8*)((ushort_t*)(ws + O_XSL) + dst) = L8;
  } else {                 // ---- enc L1 (VALU): 16 rows/block ----
    float* slots1 = ws + O_SLOTS1;
    float* h1raw  = ws + O_H1RAW;
    int bkl = bk - 512;
    int r0 = bkl * 16;
    for (int i = t; i < 64 * DIN; i += 256) sm.e1.w1L[i] = w1[i];
    for (int i = t; i < 16 * 104; i += 256) {
      int r = i / 104, c2 = i - r * 104;
      float v = 0.f;
      if (c2 < DIN) { v = x[(size_t)(r0 + r) * DIN + c2]; if (c2 >= 100) v *= 100.f; }
      sm.e1.xr[r][c2] = v;
    }
    __syncthreads();
#pragma unroll
    for (int i = 0; i < 4; ++i) {
      int idx = t + i * 256;
      int r = idx >> 6, j = idx & 63;
      float acc = b1[j];
      for (int k = 0; k < DIN; ++k) acc = fmaf(sm.e1.xr[r][k], sm.e1.w1L[j * DIN + k], acc);
      sm.e1.hb[r][j] = acc;
      h1raw[(size_t)(r0 + r) * 64 + j] = acc;
    }
    __syncthreads();
    if (t < 64) {
      float s = 0.f, qq = 0.f;
      for (int r = 0; r < 16; ++r) { float v = sm.e1.hb[r][t]; s += v; qq += v * v; }
      slots1[bkl * 128 + t] = s;
      slots1[bkl * 128 + 64 + t] = qq;
    }
  }
}

// ================= K2: k_mega — enc2 | gate | gen1-staged | gen2-staged | gen3 =================
__global__ __launch_bounds__(512) void k_mega(
    const float* __restrict__ gamma1, const float* __restrict__ beta1,
    const float* __restrict__ w2, const float* __restrict__ b2,
    const float* __restrict__ gamma2, const float* __restrict__ beta2,
    const float* __restrict__ gw1, const float* __restrict__ gb1,
    const float* __restrict__ gw2, const float* __restrict__ gb2,
    const float* __restrict__ gw3, const float* __restrict__ gb3,
    const float* __restrict__ eb1, const float* __restrict__ eb2,
    const float* __restrict__ eb3,
    float* __restrict__ ws, float* __restrict__ out) {
  __shared__ union {
    struct { float w2T[64 * 33]; float red[128]; float sc1[64], sh1[64];
             float h1b[16][64]; } enc2;
    struct { float gw1L[64 * 33]; float gw2L[64 * 65]; float gw3L[8 * 65];
             float gb1L[64], gb2L[64], gb3L[8];
             float red2[64], sc2[32], sh2[32];
             float lat[16][32]; float g1[16][64], g2[16][64]; } gate;
    struct { ushort_t stage[32 * 512]; float hT4[4][64][17]; float ebs[512]; } gen;
    struct { float p3s[8][16][64]; float eb3L[8][64]; } g3;
  } U;
  __shared__ float hb2s[16][32];      // P1 -> P2a (own msub)
  __shared__ float bc4L[4][16][8];    // P2b -> P3 (mg's 4 msubs)
  __shared__ float bcL2[16][8];       // P2a -> P4 (own msub)

  const int blk = blockIdx.x, t = threadIdx.x;
  const int wv = t >> 6, l = t & 63, c = l & 15, quad = l >> 4;
  const int msub = blk;               // role for P1 / P2a / P4
  const int R0 = msub * 16;
  const int mg = blk >> 2, g = blk & 3;   // role for P2b / P3
  const int ml = wv >> 1, nsp = wv & 1;   // wave's msub-local, ns-pair
  const int m_w = mg * 4 + ml;            // wave's msub in P2b/P3
  unsigned* bar = (unsigned*)(ws + O_BAR);
  float* bcg = ws + O_BCG;
  const ushort_t* XsH = (const ushort_t*)(ws + O_XSH);
  const ushort_t* XsL = (const ushort_t*)(ws + O_XSL);
  const ushort_t* E1H = (const ushort_t*)(ws + O_E1H);
  const ushort_t* E1L = (const ushort_t*)(ws + O_E1L);
  const ushort_t* E2H = (const ushort_t*)(ws + O_E2H);
  const ushort_t* E3H = (const ushort_t*)(ws + O_E3H);
  ushort_t* A1Hp = (ushort_t*)(ws + O_A1H);
  ushort_t* A1Lp = (ushort_t*)(ws + O_A1L);
  ushort_t* A2Hp = (ushort_t*)(ws + O_A2H);
  ushort_t* A2Lp = (ushort_t*)(ws + O_A2L);

  // early Xs A-fragment loads for wave's P2b msub (K1 output, plain cached)
  bf16x8 a1h[4], a1l[4];
#pragma unroll
  for (int kc = 0; kc < 4; ++kc) {
    a1h[kc] = *(const bf16x8*)(XsH + ((size_t)m_w * 4 + kc) * 512 + l * 8);
    a1l[kc] = *(const bf16x8*)(XsL + ((size_t)m_w * 4 + kc) * 512 + l * 8);
  }

  // ---------- P1: enc2 for own 16 rows (hb2s in LDS; slots2 write-through) ----------
  {
    const float* slots1 = ws + O_SLOTS1;
    float* slots2 = ws + O_SLOTS2;
    const float* h1raw = ws + O_H1RAW;
    for (int i = t; i < 2048; i += 512) { int j = i >> 6, k = i & 63; U.enc2.w2T[k * 33 + j] = w2[i]; }
    if (t < 128) {
      float s = 0.f;
      for (int b = 0; b < 64; ++b) s += slots1[b * 128 + t];
      U.enc2.red[t] = s;
    }
    __syncthreads();
    if (t < 64) {
      float mm = U.enc2.red[t] * (1.f / 1024.f);
      float v = U.enc2.red[64 + t] * (1.f / 1024.f) - mm * mm;
      float sc = gamma1[t] * rsqrtf(v + EPSBN);
      U.enc2.sc1[t] = sc; U.enc2.sh1[t] = beta1[t] - mm * sc;
    }
    __syncthreads();
#pragma unroll
    for (int i = 0; i < 2; ++i) {
      int idx = t + i * 512;
      int r = idx >> 6, k = idx & 63;
      U.enc2.h1b[r][k] = fmaxf(fmaf(h1raw[(size_t)(R0 + r) * 64 + k], U.enc2.sc1[k], U.enc2.sh1[k]), 0.f);
    }
    __syncthreads();
    {
      int r = t >> 5, j = t & 31;              // 512 = 16 x 32
      float acc = b2[j];
      for (int k = 0; k < 64; ++k) acc = fmaf(U.enc2.h1b[r][k], U.enc2.w2T[k * 33 + j], acc);
      hb2s[r][j] = acc;
    }
    __syncthreads();
    if (t < 32) {
      float s = 0.f, q = 0.f;
      for (int r = 0; r < 16; ++r) { float v = hb2s[r][t]; s += v; q += v * v; }
      stA(slots2 + msub * 64 + t, s);
      stA(slots2 + msub * 64 + 32 + t, q);
    }
  }
  gbar64(bar, blk);

  // ---------- P2a: gate for own 16 rows (verbatim) + bcg write-through ----------
  {
    const float* slots2 = ws + O_SLOTS2;
    for (int i = t; i < 2048; i += 512) { int j = i >> 5, k = i & 31; U.gate.gw1L[j * 33 + k] = gw1[i]; }
    for (int i = t; i < 4096; i += 512) { int j = i >> 6, k = i & 63; U.gate.gw2L[j * 65 + k] = gw2[i]; }
    { int j = t >> 6, k = t & 63; U.gate.gw3L[j * 65 + k] = gw3[t]; }
    if (t < 64) { U.gate.gb1L[t] = gb1[t]; U.gate.gb2L[t] = gb2[t]; }
    if (t < 8) U.gate.gb3L[t] = gb3[t];
    if (t < 64) {
      float vvv[64];
#pragma unroll
      for (int b = 0; b < 64; ++b) vvv[b] = ldA(slots2 + b * 64 + t);
      float s = 0.f;
#pragma unroll
      for (int b = 0; b < 64; ++b) s += vvv[b];            // same order -> bit-identical
      U.gate.red2[t] = s;
    }
    __syncthreads();
    if (t < 32) {
      float mm = U.gate.red2[t] * (1.f / 1024.f);
      float v = U.gate.red2[32 + t] * (1.f / 1024.f) - mm * mm;
      float sc = gamma2[t] * rsqrtf(v + EPSBN);
      U.gate.sc2[t] = sc; U.gate.sh2[t] = beta2[t] - mm * sc;
    }
    __syncthreads();
    { int r = t >> 5, cc = t & 31;
      U.gate.lat[r][cc] = fmaxf(fmaf(hb2s[r][cc], U.gate.sc2[cc], U.gate.sh2[cc]), 0.f); }
    __syncthreads();
#pragma unroll
    for (int rr = 0; rr < 2; ++rr) {
      int r = wv * 2 + rr;
      float a1 = U.gate.gb1L[l];
      for (int k = 0; k < 32; ++k) a1 = fmaf(U.gate.gw1L[l * 33 + k], U.gate.lat[r][k], a1);
      U.gate.g1[r][l] = eluf(a1);
    }
    __syncthreads();
#pragma unroll
    for (int rr = 0; rr < 2; ++rr) {
      int r = wv * 2 + rr;
      float a2 = U.gate.gb2L[l];
      for (int k = 0; k < 64; ++k) a2 = fmaf(U.gate.gw2L[l * 65 + k], U.gate.g1[r][k], a2);
      U.gate.g2[r][l] = eluf(a2);
    }
    __syncthreads();
#pragma unroll
    for (int rr = 0; rr < 2; ++rr) {
      int r = wv * 2 + rr;
      if (l < 8) {
        float a3 = U.gate.gb3L[l];
        for (int k = 0; k < 64; ++k) a3 = fmaf(U.gate.gw3L[l * 65 + k], U.gate.g2[r][k], a3);
        float mx = a3;
        mx = fmaxf(mx, __shfl_xor(mx, 1));
        mx = fmaxf(mx, __shfl_xor(mx, 2));
        mx = fmaxf(mx, __shfl_xor(mx, 4));
        float p = expf(a3 - mx);
        float sp = p;
        sp += __shfl_xor(sp, 1); sp += __shfl_xor(sp, 2); sp += __shfl_xor(sp, 4);
        float bcv = p / sp;
        bcL2[r][l] = bcv;                                  // own msub, persists to P4
        stA(bcg + (size_t)(R0 + r) * 8 + l, bcv);          // publish for P2b consumers
      }
    }
  }
  gbar64(bar + 1024, blk);

  // ---------- P2b: gen1 staged — block (mg,g), 4 msubs x g's 4 ns ----------
  {
    { int mli = t >> 7, r = (t >> 3) & 15, e = t & 7;      // 512 = 4 x 16 x 8
      bc4L[mli][r][e] = ldA(bcg + ((size_t)(mg * 4 + mli) * 16 + r) * 8 + e); }
    { U.gen.ebs[t] = eb1[(t >> 6) * HH + g * 64 + (t & 63)]; }
    f32x4 blend[2] = {};
    for (int e = 0; e < 8; ++e) {
      __syncthreads();                                     // covers bc4L/ebs on e=0
#pragma unroll
      for (int i = 0; i < 4; ++i) {                        // stage 32 slabs (1 KB each)
        int s = wv * 4 + i;
        int hl = s >> 4, nsl = (s >> 2) & 3, kc = s & 3;
        const ushort_t* src = (hl ? E1L : E1H) + (((size_t)(e * 16 + g * 4 + nsl) * 4 + kc) * 512) + l * 8;
        *(us8*)(U.gen.stage + s * 512 + l * 8) = *(const us8*)src;
      }
      __syncthreads();
      float bcv[4];
#pragma unroll
      for (int r = 0; r < 4; ++r) bcv[r] = bc4L[ml][quad * 4 + r][e];
#pragma unroll
      for (int nsi = 0; nsi < 2; ++nsi) {
        int nsl = nsp * 2 + nsi;
        f32x4 acc = {};
#pragma unroll
        for (int kc = 0; kc < 4; ++kc) {
          bf16x8 bh = *(const bf16x8*)(U.gen.stage + (size_t)((nsl * 4 + kc)) * 512 + l * 8);
          bf16x8 bl = *(const bf16x8*)(U.gen.stage + (size_t)((16 + nsl * 4 + kc)) * 512 + l * 8);
          acc = MFMA(a1h[kc], bh, acc, 0, 0, 0);
          acc = MFMA(a1l[kc], bh, acc, 0, 0, 0);
          acc = MFMA(a1h[kc], bl, acc, 0, 0, 0);
        }
        float ebv = U.gen.ebs[e * 64 + nsl * 16 + c];
#pragma unroll
        for (int r = 0; r < 4; ++r) blend[nsi][r] = fmaf(bcv[r], acc[r] + ebv, blend[nsi][r]);
      }
    }
#pragma unroll
    for (int nsi = 0; nsi < 2; ++nsi) {
      int col = (nsp * 2 + nsi) * 16 + c;
#pragma unroll
      for (int r = 0; r < 4; ++r) U.gen.hT4[ml][col][quad * 4 + r] = eluf(blend[nsi][r]);
    }
    __syncthreads();
    {   // repack: 512 thr = 4 msub x 2 kc-chunks x 64 lanes -> A1 slices write-through
      int mli = t >> 7, kcl = (t >> 6) & 1, l2 = t & 63, row = l2 & 15;
      int k0l = kcl * 32 + (l2 >> 4) * 8;
      us8 H, L;
#pragma unroll
      for (int j = 0; j < 8; ++j) {
        unsigned short h, lo; split_bf16(U.gen.hT4[mli][k0l + j][row], h, lo);
        H[j] = h; L[j] = lo;
      }
      size_t dst = ((size_t)(mg * 4 + mli) * 8 + g * 2 + kcl) * 512 + l2 * 8;
      st16A(A1Hp + dst, H);
      st16A(A1Lp + dst, L);
    }
  }
  gbar64(bar + 2048, blk);

  // ---------- P3: gen2 staged — block (mg,g), A1 full per wave's msub ----------
  {
    bf16x8 ah[8], al[8];
#pragma unroll
    for (int kc = 0; kc < 8; ++kc) {
      ah[kc] = ld16A(A1Hp + ((size_t)m_w * 8 + kc) * 512 + l * 8);
      al[kc] = ld16A(A1Lp + ((size_t)m_w * 8 + kc) * 512 + l * 8);
    }
    { U.gen.ebs[t] = eb2[(t >> 6) * HH + g * 64 + (t & 63)]; }
    f32x4 blend[2] = {};
    for (int e = 0; e < 8; ++e) {
      __syncthreads();
#pragma unroll
      for (int i = 0; i < 4; ++i) {                        // stage 32 slabs (hi only)
        int s = wv * 4 + i;
        int nsl = s >> 3, kc = s & 7;
        const ushort_t* src = E2H + (((size_t)(e * 16 + g * 4 + nsl) * 8 + kc) * 512) + l * 8;
        *(us8*)(U.gen.stage + s * 512 + l * 8) = *(const us8*)src;
      }
      __syncthreads();
      float bcv[4];
#pragma unroll
      for (int r = 0; r < 4; ++r) bcv[r] = bc4L[ml][quad * 4 + r][e];
#pragma unroll
      for (int nsi = 0; nsi < 2; ++nsi) {
        int nsl = nsp * 2 + nsi;
        f32x4 acc = {};
#pragma unroll
        for (int kc = 0; kc < 8; ++kc) {
          bf16x8 bh = *(const bf16x8*)(U.gen.stage + (size_t)(nsl * 8 + kc) * 512 + l * 8);
          acc = MFMA(ah[kc], bh, acc, 0, 0, 0);
          acc = MFMA(al[kc], bh, acc, 0, 0, 0);
        }
        float ebv = U.gen.ebs[e * 64 + nsl * 16 + c];
#pragma unroll
        for (int r = 0; r < 4; ++r) blend[nsi][r] = fmaf(bcv[r], acc[r] + ebv, blend[nsi][r]);
      }
    }
#pragma unroll
    for (int nsi = 0; nsi < 2; ++nsi) {
      int col = (nsp * 2 + nsi) * 16 + c;
#pragma unroll
      for (int r = 0; r < 4; ++r) U.gen.hT4[ml][col][quad * 4 + r] = eluf(blend[nsi][r]);
    }
    __syncthreads();
    {
      int mli = t >> 7, kcl = (t >> 6) & 1, l2 = t & 63, row = l2 & 15;
      int k0l = kcl * 32 + (l2 >> 4) * 8;
      us8 H, L;
#pragma unroll
      for (int j = 0; j < 8; ++j) {
        unsigned short h, lo; split_bf16(U.gen.hT4[mli][k0l + j][row], h, lo);
        H[j] = h; L[j] = lo;
      }
      size_t dst = ((size_t)(mg * 4 + mli) * 8 + g * 2 + kcl) * 512 + l2 * 8;
      st16A(A2Hp + dst, H);
      st16A(A2Lp + dst, L);
    }
  }
  gbar64(bar + 3072, blk);

  // ---------- P4: gen3 for own msub (8 waves = experts) + reduce -> out ----------
  {
    { int e = t >> 6, n = t & 63; U.g3.eb3L[e][n] = (n < DOUT) ? eb3[e * DOUT + n] : 0.f; }
    bf16x8 ah[8], al[8];
#pragma unroll
    for (int kc = 0; kc < 8; ++kc) {
      ah[kc] = ld16A(A2Hp + ((size_t)msub * 8 + kc) * 512 + l * 8);
      al[kc] = ld16A(A2Lp + ((size_t)msub * 8 + kc) * 512 + l * 8);
    }
    const int e = wv;
    f32x4 acc[4] = {};
#pragma unroll
    for (int kc = 0; kc < 8; ++kc) {
#pragma unroll
      for (int nsi = 0; nsi < 4; ++nsi) {
        size_t bo = (((size_t)(e * 4 + nsi)) * 8 + kc) * 512 + l * 8;
        bf16x8 bh = *(const bf16x8*)(E3H + bo);
        acc[nsi] = MFMA(ah[kc], bh, acc[nsi], 0, 0, 0);
        acc[nsi] = MFMA(al[kc], bh, acc[nsi], 0, 0, 0);
      }
    }
#pragma unroll
    for (int nsi = 0; nsi < 4; ++nsi)
#pragma unroll
      for (int r = 0; r < 4; ++r)
        U.g3.p3s[e][quad * 4 + r][nsi * 16 + c] = acc[nsi][r];
    __syncthreads();
#pragma unroll
    for (int i = 0; i < 2; ++i) {
      int idx = t + i * 512;             // 1024 outputs: [16 rows][64 cols]
      int row = idx >> 6, col = idx & 63;
      float s = 0.f;
#pragma unroll
      for (int e2 = 0; e2 < 8; ++e2)
        s = fmaf(bcL2[row][e2], U.g3.p3s[e2][row][col] + U.g3.eb3L[e2][col], s);
      if (col < DOUT) out[(size_t)(R0 + row) * DOUT + col] = s;
    }
  }
}

extern "C" void kernel_launch(void* const* d_in, const int* in_sizes, int n_in,
                              void* d_out, int out_size, void* d_ws, size_t ws_size,
                              hipStream_t stream) {
  const float* x      = (const float*)d_in[0];
  const float* w1     = (const float*)d_in[1];
  const float* b1     = (const float*)d_in[2];
  const float* gamma1 = (const float*)d_in[3];
  const float* beta1  = (const float*)d_in[4];
  const float* w2     = (const float*)d_in[5];
  const float* b2     = (const float*)d_in[6];
  const float* gamma2 = (const float*)d_in[7];
  const float* beta2  = (const float*)d_in[8];
  const float* gw1    = (const float*)d_in[9];
  const float* gb1    = (const float*)d_in[10];
  const float* gw2    = (const float*)d_in[11];
  const float* gb2    = (const float*)d_in[12];
  const float* gw3    = (const float*)d_in[13];
  const float* gb3    = (const float*)d_in[14];
  const float* ew1    = (const float*)d_in[15];
  const float* eb1    = (const float*)d_in[16];
  const float* ew2    = (const float*)d_in[17];
  const float* eb2    = (const float*)d_in[18];
  const float* ew3    = (const float*)d_in[19];
  const float* eb3    = (const float*)d_in[20];
  float* wsf  = (float*)d_ws;
  float* outp = (float*)d_out;

  k_prep_enc1<<<576, 256, 0, stream>>>(x, w1, b1, ew1, ew2, ew3, wsf);
  k_mega<<<64, 512, 0, stream>>>(gamma1, beta1, w2, b2, gamma2, beta2,
                                 gw1, gb1, gw2, gb2, gw3, gb3,
                                 eb1, eb2, eb3, wsf, outp);
}

// Round 16
// 184.848 us; speedup vs baseline: 1.0450x; 1.0450x over previous
//
#include <hip/hip_runtime.h>
#include <math.h>

// Network_22892175688023 — round 26 (= R23 resubmit #3; rounds 13-15 all infra
// failures, kernel never ran; R10's same failure signature ran clean in R12 ->
// environmental). Staged generator, de-serialized. 2 stages.
//   R22 post-mortem: FETCH 10.2->7.5 MB (traffic model right) but k_mega 50->89:
//   (a) lockstep stage exposed full global latency per e-iteration;
//   (b) SQ_LDS_BANK_CONFLICT 49K->4.05M (in-loop bc4L = 4-way same-bank).
//   Fix: (1) register-prefetch pipeline — load e+1 slabs into VGPRs while MFMAing
//   e (T14); (2) hoist bcv[4][8] to regs + pull eb-term out of loop as
//   ebb = sum_e bc*eb (bit-exact: eb1/eb2 are zeros). Hot loop LDS = contiguous
//   b128 stage reads only (R17/R18-proven pattern, 49K conflicts).
//   P1/P2a/P4, barriers, A round-trips verbatim R22 (passed, absmax 3.9e-3).
//   Falsifier: k_mega >= 45us -> staging axis dead -> revert to R18, declare floor.

#define DIN 103
#define NE  8
#define HH  256
#define DOUT 51
#define EPSBN 1e-5f

typedef __attribute__((ext_vector_type(8))) short bf16x8;
typedef __attribute__((ext_vector_type(4))) float f32x4;
typedef __attribute__((ext_vector_type(8))) unsigned short us8;
typedef unsigned short ushort_t;

__device__ __forceinline__ float eluf(float v) { return v > 0.f ? v : (expf(v) - 1.f); }
__device__ __forceinline__ unsigned short bf16h(float f) {
  unsigned u = __float_as_uint(f);
  u += 0x7FFFu + ((u >> 16) & 1u);
  return (unsigned short)(u >> 16);
}
__device__ __forceinline__ float bf16f(unsigned short h) { return __uint_as_float(((unsigned)h) << 16); }
__device__ __forceinline__ void split_bf16(float v, unsigned short& h, unsigned short& l) {
  h = bf16h(v);
  l = bf16h(v - bf16f(h));
}
#define MFMA __builtin_amdgcn_mfma_f32_16x16x32_bf16

// relaxed agent-scope coherent access helpers (no cache-maintenance ops)
__device__ __forceinline__ void stA(float* p, float v) {
  __hip_atomic_store(p, v, __ATOMIC_RELAXED, __HIP_MEMORY_SCOPE_AGENT);
}
__device__ __forceinline__ float ldA(const float* p) {
  return __hip_atomic_load((float*)p, __ATOMIC_RELAXED, __HIP_MEMORY_SCOPE_AGENT);
}
__device__ __forceinline__ void stAu(unsigned* p, unsigned v) {
  __hip_atomic_store(p, v, __ATOMIC_RELAXED, __HIP_MEMORY_SCOPE_AGENT);
}
__device__ __forceinline__ unsigned ldAu(const unsigned* p) {
  return __hip_atomic_load((unsigned*)p, __ATOMIC_RELAXED, __HIP_MEMORY_SCOPE_AGENT);
}
union U16B { us8 v; bf16x8 b; unsigned u[4]; };
__device__ __forceinline__ void st16A(void* p, us8 x) {
  U16B t; t.v = x;
  unsigned* d = (unsigned*)p;
#pragma unroll
  for (int j = 0; j < 4; ++j) stAu(d + j, t.u[j]);
}
__device__ __forceinline__ bf16x8 ld16A(const void* p) {
  U16B t;
  const unsigned* s = (const unsigned*)p;
#pragma unroll
  for (int j = 0; j < 4; ++j) t.u[j] = ldAu(s + j);
  return t.b;
}

// ---- ws layout (float offsets) ----
#define O_SLOTS1 0        // [64][128]
#define O_SLOTS2 8192     // [64][64]
#define O_BCG    12288    // [1024][8]
#define O_H1RAW  20480    // [1024][64]
#define O_XSH    118784   // [64 msub][4 kc][512] sh
#define O_XSL    184320
#define O_E1H    258048   // [8 e][16 ns][4 kc][512] sh
#define O_E1L    389120
#define O_E2H    520192   // [8 e][16 ns][8 kc][512] sh  (hi only)
#define O_E3H    782336   // [8 e][4 ns][8 kc][512] sh   (hi only)
#define O_A1H    847872   // [64 m][8 kc][512] sh
#define O_A1L    978944
#define O_A2H    1110016
#define O_A2L    1241088
#define O_BAR    1372160  // 4 x 1024-dword tree-barrier regions (zeroed by K1)

// 8x8 tree barrier for 64 blocks; region: grp[i]@i*32 (i<8), root@256,
// rel[j]@288+j*32 (j<8). Each region used once per launch.
__device__ __forceinline__ void gbar64(unsigned* base, int blk) {
  asm volatile("s_waitcnt vmcnt(0)" ::: "memory");
  __syncthreads();
  if (threadIdx.x == 0) {
    unsigned a = __hip_atomic_fetch_add(base + (blk >> 3) * 32, 1u,
                                        __ATOMIC_RELAXED, __HIP_MEMORY_SCOPE_AGENT);
    if (a == 7u) {
      unsigned r = __hip_atomic_fetch_add(base + 256, 1u,
                                          __ATOMIC_RELAXED, __HIP_MEMORY_SCOPE_AGENT);
      if (r == 7u) {
#pragma unroll
        for (int j = 0; j < 8; ++j) stAu(base + 288 + j * 32, 1u);
      }
    }
    while (ldAu(base + 288 + (blk & 7) * 32) == 0u)
      __builtin_amdgcn_s_sleep(2);
  }
  __syncthreads();
}

// ================= K1: prep planes + Xs frags + enc L1 (VALU) =================
// blocks: E2 0..255 | E1 256..383 | E3 384..447 | Xs 448..511 | enc1 512..575
__global__ __launch_bounds__(256) void k_prep_enc1(
    const float* __restrict__ x, const float* __restrict__ w1, const float* __restrict__ b1,
    const float* __restrict__ ew1, const float* __restrict__ ew2, const float* __restrict__ ew3,
    float* __restrict__ ws) {
  __shared__ union {
    float tile[32][65];
    float xt[16][104];
    struct { float w1L[64 * DIN]; float xr[16][104]; float hb[16][64]; } e1;
  } sm;
  int bk = blockIdx.x, t = threadIdx.x;
  int l2 = t & 63, c = l2 & 15, q = l2 >> 4;
  if (bk < 4) {   // zero the 4 barrier regions (1024 dwords each)
    unsigned* bz = (unsigned*)(ws + O_BAR) + bk * 1024;
#pragma unroll
    for (int i = 0; i < 4; ++i) bz[t + i * 256] = 0u;
  }

  if (bk < 256) {          // ---- E2: K=256, N=256, hi only ----
    int nh = bk & 3, kc = (bk >> 2) & 7, e = bk >> 5;
    int k0 = kc * 32, n0 = nh * 64;
#pragma unroll
    for (int i = 0; i < 8; ++i) {
      int kl = (t >> 6) + i * 4;
      sm.tile[kl][t & 63] = ew2[((size_t)e * HH + k0 + kl) * HH + n0 + (t & 63)];
    }
    __syncthreads();
    int nsl = t >> 6;
    us8 H8;
#pragma unroll
    for (int j = 0; j < 8; ++j) H8[j] = bf16h(sm.tile[q * 8 + j][nsl * 16 + c]);
    size_t dst = (((size_t)(e * 16 + nh * 4 + nsl)) * 8 + kc) * 512 + l2 * 8;
    *(us8*)((ushort_t*)(ws + O_E2H) + dst) = H8;
  } else if (bk < 384) {   // ---- E1: K=103->128, N=256, hi+lo ----
    int b2 = bk - 256;
    int nh = b2 & 3, kc = (b2 >> 2) & 3, e = b2 >> 4;
    int k0 = kc * 32, n0 = nh * 64;
#pragma unroll
    for (int i = 0; i < 8; ++i) {
      int kl = (t >> 6) + i * 4;
      int k = k0 + kl;
      sm.tile[kl][t & 63] = (k < DIN) ? ew1[((size_t)e * DIN + k) * HH + n0 + (t & 63)] : 0.f;
    }
    __syncthreads();
    int nsl = t >> 6;
    us8 H8, L8;
#pragma unroll
    for (int j = 0; j < 8; ++j) {
      unsigned short h, lo; split_bf16(sm.tile[q * 8 + j][nsl * 16 + c], h, lo);
      H8[j] = h; L8[j] = lo;
    }
    size_t dst = (((size_t)(e * 16 + nh * 4 + nsl)) * 4 + kc) * 512 + l2 * 8;
    *(us8*)((ushort_t*)(ws + O_E1H) + dst) = H8;
    *(us8*)((ushort_t*)(ws + O_E1L) + dst) = L8;
  } else if (bk < 448) {   // ---- E3: K=256, N=51->64, hi only ----
    int b2 = bk - 384;
    int kc = b2 & 7, e = b2 >> 3;
    int k0 = kc * 32;
#pragma unroll
    for (int i = 0; i < 8; ++i) {
      int kl = (t >> 6) + i * 4;
      int n = t & 63;
      sm.tile[kl][n] = (n < DOUT) ? ew3[((size_t)e * HH + k0 + kl) * DOUT + n] : 0.f;
    }
    __syncthreads();
    int nsl = t >> 6;
    us8 H8;
#pragma unroll
    for (int j = 0; j < 8; ++j) H8[j] = bf16h(sm.tile[q * 8 + j][nsl * 16 + c]);
    size_t dst = (((size_t)(e * 4 + nsl)) * 8 + kc) * 512 + l2 * 8;
    *(us8*)((ushort_t*)(ws + O_E3H) + dst) = H8;
  } else if (bk < 512) {   // ---- Xs: A-fragments of scaled x, 16 rows/block, hi+lo ----
    int msub = bk - 448;
    for (int i = t; i < 16 * 104; i += 256) {
      int b = i / 104, k = i - b * 104;
      float v = 0.f;
      if (k < DIN) { v = x[(size_t)(msub * 16 + b) * DIN + k]; if (k >= 100) v *= 100.f; }
      sm.xt[b][k] = v;
    }
    __syncthreads();
    int kc = t >> 6;
    int m = c;
    us8 H8, L8;
#pragma unroll
    for (int j = 0; j < 8; ++j) {
      int k = kc * 32 + q * 8 + j;
      float v = (k < 104) ? sm.xt[m][k] : 0.f;
      unsigned short h, lo; split_bf16(v, h, lo);
      H8[j] = h; L8[j] = lo;
    }
    size_t dst = ((size_t)msub * 4 + kc) * 512 + l2 * 8;
    *(us8*)((ushort_t*)(ws + O_XSH) + dst) = H8;
    *(us8*)((ushort_t*)(ws + O_XSL) + dst) = L8;
  } else {                 // ---- enc L1 (VALU): 16 rows/block ----
    float* slots1 = ws + O_SLOTS1;
    float* h1raw  = ws + O_H1RAW;
    int bkl = bk - 512;
    int r0 = bkl * 16;
    for (int i = t; i < 64 * DIN; i += 256) sm.e1.w1L[i] = w1[i];
    for (int i = t; i < 16 * 104; i += 256) {
      int r = i / 104, c2 = i - r * 104;
      float v = 0.f;
      if (c2 < DIN) { v = x[(size_t)(r0 + r) * DIN + c2]; if (c2 >= 100) v *= 100.f; }
      sm.e1.xr[r][c2] = v;
    }
    __syncthreads();
#pragma unroll
    for (int i = 0; i < 4; ++i) {
      int idx = t + i * 256;
      int r = idx >> 6, j = idx & 63;
      float acc = b1[j];
      for (int k = 0; k < DIN; ++k) acc = fmaf(sm.e1.xr[r][k], sm.e1.w1L[j * DIN + k], acc);
      sm.e1.hb[r][j] = acc;
      h1raw[(size_t)(r0 + r) * 64 + j] = acc;
    }
    __syncthreads();
    if (t < 64) {
      float s = 0.f, qq = 0.f;
      for (int r = 0; r < 16; ++r) { float v = sm.e1.hb[r][t]; s += v; qq += v * v; }
      slots1[bkl * 128 + t] = s;
      slots1[bkl * 128 + 64 + t] = qq;
    }
  }
}

// ================= K2: k_mega — enc2 | gate | gen1-staged | gen2-staged | gen3 =================
__global__ __launch_bounds__(512) void k_mega(
    const float* __restrict__ gamma1, const float* __restrict__ beta1,
    const float* __restrict__ w2, const float* __restrict__ b2,
    const float* __restrict__ gamma2, const float* __restrict__ beta2,
    const float* __restrict__ gw1, const float* __restrict__ gb1,
    const float* __restrict__ gw2, const float* __restrict__ gb2,
    const float* __restrict__ gw3, const float* __restrict__ gb3,
    const float* __restrict__ eb1, const float* __restrict__ eb2,
    const float* __restrict__ eb3,
    float* __restrict__ ws, float* __restrict__ out) {
  __shared__ union {
    struct { float w2T[64 * 33]; float red[128]; float sc1[64], sh1[64];
             float h1b[16][64]; } enc2;
    struct { float gw1L[64 * 33]; float gw2L[64 * 65]; float gw3L[8 * 65];
             float gb1L[64], gb2L[64], gb3L[8];
             float red2[64], sc2[32], sh2[32];
             float lat[16][32]; float g1[16][64], g2[16][64]; } gate;
    struct { ushort_t stage[32 * 512]; float hT4[4][64][17]; float ebs[512]; } gen;
    struct { float p3s[8][16][64]; float eb3L[8][64]; } g3;
  } U;
  __shared__ float hb2s[16][32];      // P1 -> P2a (own msub)
  __shared__ float bc4L[4][16][8];    // P2b -> P3 (mg's 4 msubs)
  __shared__ float bcL2[16][8];       // P2a -> P4 (own msub)

  const int blk = blockIdx.x, t = threadIdx.x;
  const int wv = t >> 6, l = t & 63, c = l & 15, quad = l >> 4;
  const int msub = blk;               // role for P1 / P2a / P4
  const int R0 = msub * 16;
  const int mg = blk >> 2, g = blk & 3;   // role for P2b / P3
  const int ml = wv >> 1, nsp = wv & 1;   // wave's msub-local, ns-pair
  const int m_w = mg * 4 + ml;            // wave's msub in P2b/P3
  unsigned* bar = (unsigned*)(ws + O_BAR);
  float* bcg = ws + O_BCG;
  const ushort_t* XsH = (const ushort_t*)(ws + O_XSH);
  const ushort_t* XsL = (const ushort_t*)(ws + O_XSL);
  const ushort_t* E1H = (const ushort_t*)(ws + O_E1H);
  const ushort_t* E1L = (const ushort_t*)(ws + O_E1L);
  const ushort_t* E2H = (const ushort_t*)(ws + O_E2H);
  const ushort_t* E3H = (const ushort_t*)(ws + O_E3H);
  ushort_t* A1Hp = (ushort_t*)(ws + O_A1H);
  ushort_t* A1Lp = (ushort_t*)(ws + O_A1L);
  ushort_t* A2Hp = (ushort_t*)(ws + O_A2H);
  ushort_t* A2Lp = (ushort_t*)(ws + O_A2L);

  // early Xs A-fragment loads for wave's P2b msub (K1 output, plain cached)
  bf16x8 a1h[4], a1l[4];
#pragma unroll
  for (int kc = 0; kc < 4; ++kc) {
    a1h[kc] = *(const bf16x8*)(XsH + ((size_t)m_w * 4 + kc) * 512 + l * 8);
    a1l[kc] = *(const bf16x8*)(XsL + ((size_t)m_w * 4 + kc) * 512 + l * 8);
  }

  // ---------- P1: enc2 for own 16 rows (hb2s in LDS; slots2 write-through) ----------
  {
    const float* slots1 = ws + O_SLOTS1;
    float* slots2 = ws + O_SLOTS2;
    const float* h1raw = ws + O_H1RAW;
    for (int i = t; i < 2048; i += 512) { int j = i >> 6, k = i & 63; U.enc2.w2T[k * 33 + j] = w2[i]; }
    if (t < 128) {
      float s = 0.f;
      for (int b = 0; b < 64; ++b) s += slots1[b * 128 + t];
      U.enc2.red[t] = s;
    }
    __syncthreads();
    if (t < 64) {
      float mm = U.enc2.red[t] * (1.f / 1024.f);
      float v = U.enc2.red[64 + t] * (1.f / 1024.f) - mm * mm;
      float sc = gamma1[t] * rsqrtf(v + EPSBN);
      U.enc2.sc1[t] = sc; U.enc2.sh1[t] = beta1[t] - mm * sc;
    }
    __syncthreads();
#pragma unroll
    for (int i = 0; i < 2; ++i) {
      int idx = t + i * 512;
      int r = idx >> 6, k = idx & 63;
      U.enc2.h1b[r][k] = fmaxf(fmaf(h1raw[(size_t)(R0 + r) * 64 + k], U.enc2.sc1[k], U.enc2.sh1[k]), 0.f);
    }
    __syncthreads();
    {
      int r = t >> 5, j = t & 31;              // 512 = 16 x 32
      float acc = b2[j];
      for (int k = 0; k < 64; ++k) acc = fmaf(U.enc2.h1b[r][k], U.enc2.w2T[k * 33 + j], acc);
      hb2s[r][j] = acc;
    }
    __syncthreads();
    if (t < 32) {
      float s = 0.f, q = 0.f;
      for (int r = 0; r < 16; ++r) { float v = hb2s[r][t]; s += v; q += v * v; }
      stA(slots2 + msub * 64 + t, s);
      stA(slots2 + msub * 64 + 32 + t, q);
    }
  }
  gbar64(bar, blk);

  // ---------- P2a: gate for own 16 rows (verbatim) + bcg write-through ----------
  {
    const float* slots2 = ws + O_SLOTS2;
    for (int i = t; i < 2048; i += 512) { int j = i >> 5, k = i & 31; U.gate.gw1L[j * 33 + k] = gw1[i]; }
    for (int i = t; i < 4096; i += 512) { int j = i >> 6, k = i & 63; U.gate.gw2L[j * 65 + k] = gw2[i]; }
    { int j = t >> 6, k = t & 63; U.gate.gw3L[j * 65 + k] = gw3[t]; }
    if (t < 64) { U.gate.gb1L[t] = gb1[t]; U.gate.gb2L[t] = gb2[t]; }
    if (t < 8) U.gate.gb3L[t] = gb3[t];
    if (t < 64) {
      float vvv[64];
#pragma unroll
      for (int b = 0; b < 64; ++b) vvv[b] = ldA(slots2 + b * 64 + t);
      float s = 0.f;
#pragma unroll
      for (int b = 0; b < 64; ++b) s += vvv[b];            // same order -> bit-identical
      U.gate.red2[t] = s;
    }
    __syncthreads();
    if (t < 32) {
      float mm = U.gate.red2[t] * (1.f / 1024.f);
      float v = U.gate.red2[32 + t] * (1.f / 1024.f) - mm * mm;
      float sc = gamma2[t] * rsqrtf(v + EPSBN);
      U.gate.sc2[t] = sc; U.gate.sh2[t] = beta2[t] - mm * sc;
    }
    __syncthreads();
    { int r = t >> 5, cc = t & 31;
      U.gate.lat[r][cc] = fmaxf(fmaf(hb2s[r][cc], U.gate.sc2[cc], U.gate.sh2[cc]), 0.f); }
    __syncthreads();
#pragma unroll
    for (int rr = 0; rr < 2; ++rr) {
      int r = wv * 2 + rr;
      float a1 = U.gate.gb1L[l];
      for (int k = 0; k < 32; ++k) a1 = fmaf(U.gate.gw1L[l * 33 + k], U.gate.lat[r][k], a1);
      U.gate.g1[r][l] = eluf(a1);
    }
    __syncthreads();
#pragma unroll
    for (int rr = 0; rr < 2; ++rr) {
      int r = wv * 2 + rr;
      float a2 = U.gate.gb2L[l];
      for (int k = 0; k < 64; ++k) a2 = fmaf(U.gate.gw2L[l * 65 + k], U.gate.g1[r][k], a2);
      U.gate.g2[r][l] = eluf(a2);
    }
    __syncthreads();
#pragma unroll
    for (int rr = 0; rr < 2; ++rr) {
      int r = wv * 2 + rr;
      if (l < 8) {
        float a3 = U.gate.gb3L[l];
        for (int k = 0; k < 64; ++k) a3 = fmaf(U.gate.gw3L[l * 65 + k], U.gate.g2[r][k], a3);
        float mx = a3;
        mx = fmaxf(mx, __shfl_xor(mx, 1));
        mx = fmaxf(mx, __shfl_xor(mx, 2));
        mx = fmaxf(mx, __shfl_xor(mx, 4));
        float p = expf(a3 - mx);
        float sp = p;
        sp += __shfl_xor(sp, 1); sp += __shfl_xor(sp, 2); sp += __shfl_xor(sp, 4);
        float bcv = p / sp;
        bcL2[r][l] = bcv;                                  // own msub, persists to P4
        stA(bcg + (size_t)(R0 + r) * 8 + l, bcv);          // publish for P2b consumers
      }
    }
  }
  gbar64(bar + 1024, blk);

  // ---------- P2b: gen1 staged, register-prefetch pipeline ----------
  {
    { int mli = t >> 7, r = (t >> 3) & 15, e = t & 7;      // 512 = 4 x 16 x 8
      bc4L[mli][r][e] = ldA(bcg + ((size_t)(mg * 4 + mli) * 16 + r) * 8 + e); }
    { U.gen.ebs[t] = eb1[(t >> 6) * HH + g * 64 + (t & 63)]; }
    // per-i slab source/dest bases (e = 0)
    const ushort_t* srcb[4];
    ushort_t* dstb[4];
#pragma unroll
    for (int i = 0; i < 4; ++i) {
      int s = wv * 4 + i;
      int hl = s >> 4, nsl = (s >> 2) & 3, kc = s & 3;
      srcb[i] = (hl ? E1L : E1H) + (((size_t)(g * 4 + nsl) * 4 + kc) * 512) + l * 8;
      dstb[i] = U.gen.stage + s * 512 + l * 8;
    }
    us8 pf[4];
#pragma unroll
    for (int i = 0; i < 4; ++i) pf[i] = *(const us8*)srcb[i];     // prefetch e=0
    __syncthreads();                                   // bc4L / ebs visible
    // hoist bc to registers (kills in-loop 4-way same-bank LDS reads)
    float bcv[4][8];
#pragma unroll
    for (int r = 0; r < 4; ++r)
#pragma unroll
      for (int e = 0; e < 8; ++e) bcv[r][e] = bc4L[ml][quad * 4 + r][e];
    // eb part hoisted out of the loop: ebb = sum_e bc*eb (eb1 == 0 -> bit-exact)
    float ebb[2][4];
#pragma unroll
    for (int nsi = 0; nsi < 2; ++nsi) {
      int nsl = nsp * 2 + nsi;
#pragma unroll
      for (int r = 0; r < 4; ++r) {
        float s = 0.f;
#pragma unroll
        for (int e = 0; e < 8; ++e) s = fmaf(bcv[r][e], U.gen.ebs[e * 64 + nsl * 16 + c], s);
        ebb[nsi][r] = s;
      }
    }
    f32x4 blend[2] = {};
    for (int e = 0; e < 8; ++e) {
      __syncthreads();                                 // stage free (prev reads done)
#pragma unroll
      for (int i = 0; i < 4; ++i) *(us8*)dstb[i] = pf[i];
      if (e < 7) {                                     // issue next-e loads (latency
#pragma unroll                                         //  spans the whole iteration)
        for (int i = 0; i < 4; ++i) pf[i] = *(const us8*)(srcb[i] + (size_t)(e + 1) * 32768);
      }
      __syncthreads();                                 // stage ready
#pragma unroll
      for (int nsi = 0; nsi < 2; ++nsi) {
        int nsl = nsp * 2 + nsi;
        f32x4 acc = {};
#pragma unroll
        for (int kc = 0; kc < 4; ++kc) {
          bf16x8 bh = *(const bf16x8*)(U.gen.stage + (size_t)(nsl * 4 + kc) * 512 + l * 8);
          bf16x8 bl = *(const bf16x8*)(U.gen.stage + (size_t)(16 + nsl * 4 + kc) * 512 + l * 8);
          acc = MFMA(a1h[kc], bh, acc, 0, 0, 0);
          acc = MFMA(a1l[kc], bh, acc, 0, 0, 0);
          acc = MFMA(a1h[kc], bl, acc, 0, 0, 0);
        }
#pragma unroll
        for (int r = 0; r < 4; ++r) blend[nsi][r] = fmaf(bcv[r][e], acc[r], blend[nsi][r]);
      }
    }
#pragma unroll
    for (int nsi = 0; nsi < 2; ++nsi) {
      int col = (nsp * 2 + nsi) * 16 + c;
#pragma unroll
      for (int r = 0; r < 4; ++r)
        U.gen.hT4[ml][col][quad * 4 + r] = eluf(blend[nsi][r] + ebb[nsi][r]);
    }
    __syncthreads();
    {   // repack: 512 thr = 4 msub x 2 kc-chunks x 64 lanes -> A1 slices write-through
      int mli = t >> 7, kcl = (t >> 6) & 1, l2 = t & 63, row = l2 & 15;
      int k0l = kcl * 32 + (l2 >> 4) * 8;
      us8 H, L;
#pragma unroll
      for (int j = 0; j < 8; ++j) {
        unsigned short h, lo; split_bf16(U.gen.hT4[mli][k0l + j][row], h, lo);
        H[j] = h; L[j] = lo;
      }
      size_t dst = ((size_t)(mg * 4 + mli) * 8 + g * 2 + kcl) * 512 + l2 * 8;
      st16A(A1Hp + dst, H);
      st16A(A1Lp + dst, L);
    }
  }
  gbar64(bar + 2048, blk);

  // ---------- P3: gen2 staged, register-prefetch pipeline ----------
  {
    bf16x8 ah[8], al[8];
#pragma unroll
    for (int kc = 0; kc < 8; ++kc) {
      ah[kc] = ld16A(A1Hp + ((size_t)m_w * 8 + kc) * 512 + l * 8);
      al[kc] = ld16A(A1Lp + ((size_t)m_w * 8 + kc) * 512 + l * 8);
    }
    { U.gen.ebs[t] = eb2[(t >> 6) * HH + g * 64 + (t & 63)]; }
    const ushort_t* srcb[4];
    ushort_t* dstb[4];
#pragma unroll
    for (int i = 0; i < 4; ++i) {
      int s = wv * 4 + i;
      int nsl = s >> 3, kc = s & 7;
      srcb[i] = E2H + (((size_t)(g * 4 + nsl) * 8 + kc) * 512) + l * 8;
      dstb[i] = U.gen.stage + s * 512 + l * 8;
    }
    us8 pf[4];
#pragma unroll
    for (int i = 0; i < 4; ++i) pf[i] = *(const us8*)srcb[i];     // prefetch e=0
    __syncthreads();                                   // ebs visible (bc4L from P2b)
    float bcv[4][8];
#pragma unroll
    for (int r = 0; r < 4; ++r)
#pragma unroll
      for (int e = 0; e < 8; ++e) bcv[r][e] = bc4L[ml][quad * 4 + r][e];
    float ebb[2][4];
#pragma unroll
    for (int nsi = 0; nsi < 2; ++nsi) {
      int nsl = nsp * 2 + nsi;
#pragma unroll
      for (int r = 0; r < 4; ++r) {
        float s = 0.f;
#pragma unroll
        for (int e = 0; e < 8; ++e) s = fmaf(bcv[r][e], U.gen.ebs[e * 64 + nsl * 16 + c], s);
        ebb[nsi][r] = s;
      }
    }
    f32x4 blend[2] = {};
    for (int e = 0; e < 8; ++e) {
      __syncthreads();
#pragma unroll
      for (int i = 0; i < 4; ++i) *(us8*)dstb[i] = pf[i];
      if (e < 7) {
#pragma unroll
        for (int i = 0; i < 4; ++i) pf[i] = *(const us8*)(srcb[i] + (size_t)(e + 1) * 65536);
      }
      __syncthreads();
#pragma unroll
      for (int nsi = 0; nsi < 2; ++nsi) {
        int nsl = nsp * 2 + nsi;
        f32x4 acc = {};
#pragma unroll
        for (int kc = 0; kc < 8; ++kc) {
          bf16x8 bh = *(const bf16x8*)(U.gen.stage + (size_t)(nsl * 8 + kc) * 512 + l * 8);
          acc = MFMA(ah[kc], bh, acc, 0, 0, 0);
          acc = MFMA(al[kc], bh, acc, 0, 0, 0);
        }
#pragma unroll
        for (int r = 0; r < 4; ++r) blend[nsi][r] = fmaf(bcv[r][e], acc[r], blend[nsi][r]);
      }
    }
#pragma unroll
    for (int nsi = 0; nsi < 2; ++nsi) {
      int col = (nsp * 2 + nsi) * 16 + c;
#pragma unroll
      for (int r = 0; r < 4; ++r)
        U.gen.hT4[ml][col][quad * 4 + r] = eluf(blend[nsi][r] + ebb[nsi][r]);
    }
    __syncthreads();
    {
      int mli = t >> 7, kcl = (t >> 6) & 1, l2 = t & 63, row = l2 & 15;
      int k0l = kcl * 32 + (l2 >> 4) * 8;
      us8 H, L;
#pragma unroll
      for (int j = 0; j < 8; ++j) {
        unsigned short h, lo; split_bf16(U.gen.hT4[mli][k0l + j][row], h, lo);
        H[j] = h; L[j] = lo;
      }
      size_t dst = ((size_t)(mg * 4 + mli) * 8 + g * 2 + kcl) * 512 + l2 * 8;
      st16A(A2Hp + dst, H);
      st16A(A2Lp + dst, L);
    }
  }
  gbar64(bar + 3072, blk);

  // ---------- P4: gen3 for own msub (8 waves = experts) + reduce -> out ----------
  {
    { int e = t >> 6, n = t & 63; U.g3.eb3L[e][n] = (n < DOUT) ? eb3[e * DOUT + n] : 0.f; }
    bf16x8 ah[8], al[8];
#pragma unroll
    for (int kc = 0; kc < 8; ++kc) {
      ah[kc] = ld16A(A2Hp + ((size_t)msub * 8 + kc) * 512 + l * 8);
      al[kc] = ld16A(A2Lp + ((size_t)msub * 8 + kc) * 512 + l * 8);
    }
    const int e = wv;
    f32x4 acc[4] = {};
#pragma unroll
    for (int kc = 0; kc < 8; ++kc) {
#pragma unroll
      for (int nsi = 0; nsi < 4; ++nsi) {
        size_t bo = (((size_t)(e * 4 + nsi)) * 8 + kc) * 512 + l * 8;
        bf16x8 bh = *(const bf16x8*)(E3H + bo);
        acc[nsi] = MFMA(ah[kc], bh, acc[nsi], 0, 0, 0);
        acc[nsi] = MFMA(al[kc], bh, acc[nsi], 0, 0, 0);
      }
    }
#pragma unroll
    for (int nsi = 0; nsi < 4; ++nsi)
#pragma unroll
      for (int r = 0; r < 4; ++r)
        U.g3.p3s[e][quad * 4 + r][nsi * 16 + c] = acc[nsi][r];
    __syncthreads();
#pragma unroll
    for (int i = 0; i < 2; ++i) {
      int idx = t + i * 512;             // 1024 outputs: [16 rows][64 cols]
      int row = idx >> 6, col = idx & 63;
      float s = 0.f;
#pragma unroll
      for (int e2 = 0; e2 < 8; ++e2)
        s = fmaf(bcL2[row][e2], U.g3.p3s[e2][row][col] + U.g3.eb3L[e2][col], s);
      if (col < DOUT) out[(size_t)(R0 + row) * DOUT + col] = s;
    }
  }
}

extern "C" void kernel_launch(void* const* d_in, const int* in_sizes, int n_in,
                              void* d_out, int out_size, void* d_ws, size_t ws_size,
                              hipStream_t stream) {
  const float* x      = (const float*)d_in[0];
  const float* w1     = (const float*)d_in[1];
  const float* b1     = (const float*)d_in[2];
  const float* gamma1 = (const float*)d_in[3];
  const float* beta1  = (const float*)d_in[4];
  const float* w2     = (const float*)d_in[5];
  const float* b2     = (const float*)d_in[6];
  const float* gamma2 = (const float*)d_in[7];
  const float* beta2  = (const float*)d_in[8];
  const float* gw1    = (const float*)d_in[9];
  const float* gb1    = (const float*)d_in[10];
  const float* gw2    = (const float*)d_in[11];
  const float* gb2    = (const float*)d_in[12];
  const float* gw3    = (const float*)d_in[13];
  const float* gb3    = (const float*)d_in[14];
  const float* ew1    = (const float*)d_in[15];
  const float* eb1    = (const float*)d_in[16];
  const float* ew2    = (const float*)d_in[17];
  const float* eb2    = (const float*)d_in[18];
  const float* ew3    = (const float*)d_in[19];
  const float* eb3    = (const float*)d_in[20];
  float* wsf  = (float*)d_ws;
  float* outp = (float*)d_out;

  k_prep_enc1<<<576, 256, 0, stream>>>(x, w1, b1, ew1, ew2, ew3, wsf);
  k_mega<<<64, 512, 0, stream>>>(gamma1, beta1, w2, b2, gamma2, beta2,
                                 gw1, gb1, gw2, gb2, gw3, gb3,
                                 eb1, eb2, eb3, wsf, outp);
}